// Round 8
// baseline (2293.933 us; speedup 1.0000x reference)
//
#include <hip/hip_runtime.h>

#define NB 2
#define NN 1024
#define HID 512
#define NHD 8
#define HD 64
#define NE 16

// ---- K0: mask dtype detection: 0=int32, 1=uint8-packed, 2=fp32, 3=int64 ----
__global__ __launch_bounds__(256) void k_maskdet(const unsigned int* __restrict__ m,
                                                 int* __restrict__ flag) {
    __shared__ int sh;
    if (threadIdx.x == 0) sh = 0;
    __syncthreads();
    int loc = 0;
    for (int i = threadIdx.x; i < 4096; i += 256) {  // 16 KB prefix, in-bounds for all encodings
        unsigned v = m[i];
        if (v == 0x3F800000u) loc |= 1;              // fp32 1.0 marker
        else if (v > 1u) loc |= 2;                   // packed-byte marker
        else if (v != 0u) loc |= (i & 1) ? 4 : 8;    // nonzero at odd / even word index
    }
    if (loc) atomicOr(&sh, loc);
    __syncthreads();
    if (threadIdx.x == 0) {
        int s = sh;
        int mode;
        if (s & 1) mode = 2;                          // fp32
        else if (s & 2) mode = 1;                     // uint8
        else if ((s & 8) && !(s & 4)) mode = 3;       // int64: ones only in (even) low words
        else mode = 0;                                // int32
        *flag = mode;
    }
}

// ---- K1: QKV projection, fp32 out, one thread per output element ----
__global__ __launch_bounds__(256) void k_qkv_f(
    const float* __restrict__ x,
    const float* __restrict__ Wq, const float* __restrict__ Wk, const float* __restrict__ Wv,
    const float* __restrict__ bq, const float* __restrict__ bk, const float* __restrict__ bv,
    float* __restrict__ qb, float* __restrict__ kb, float* __restrict__ vt) {
    int t = blockIdx.x * 256 + threadIdx.x;
    int which = t / (2048 * 512);
    int rem = t % (2048 * 512);
    int m = rem >> 9, n = rem & 511;
    const float* W = (which == 0) ? Wq : (which == 1) ? Wk : Wv;
    const float* bias = (which == 0) ? bq : (which == 1) ? bk : bv;
    const float* xr = x + (size_t)m * HID;
    float acc = bias[n];
    for (int k = 0; k < HID; k++) acc += xr[k] * W[(size_t)k * HID + n];
    int b = m >> 10, tok = m & 1023, h = n >> 6, d = n & 63;
    if (which == 0)      qb[((size_t)(b * NHD + h) * NN + tok) * HD + d] = acc;
    else if (which == 1) kb[((size_t)(b * NHD + h) * NN + tok) * HD + d] = acc;
    else                 vt[((size_t)(b * NHD + h) * HD + d) * NN + tok] = acc;  // V^T (b,h,d,tok)
}

// ---- K2: scores with INLINE edge-MLP + mask + softmax -> attn (FP32, d_out; write-only) ----
__global__ __launch_bounds__(256) void k_escore(
    const float* __restrict__ qb, const float* __restrict__ kb, const float* __restrict__ ef,
    const float* __restrict__ We1, const float* __restrict__ be1,
    const float* __restrict__ We2, const float* __restrict__ be2,
    const void* __restrict__ mask, const int* __restrict__ mode_p,
    float* __restrict__ attn) {
    __shared__ float w1[16][16], w2[16][8], b1s[16], b2s[8];
    int tid = threadIdx.x;
    w1[tid >> 4][tid & 15] = We1[tid];
    if (tid < 128) w2[tid >> 3][tid & 7] = We2[tid];
    if (tid < 16) b1s[tid] = be1[tid];
    if (tid < 8)  b2s[tid] = be2[tid];
    __syncthreads();
    int mode = *mode_p;
    int wv = tid >> 6, lane = tid & 63;
    int row = blockIdx.x * 4 + wv;            // row = (b*NHD+h)*NN + q
    int b = row >> 13, h = (row >> 10) & 7, qi = row & 1023;
    const float* qrow = qb + (size_t)row * HD;
    float qf[64];
    for (int d = 0; d < 64; d++) qf[d] = qrow[d];
    const float* kbh = kb + (size_t)(row >> 10) * NN * HD;
    const float* efrow = ef + ((size_t)b * NN + qi) * NN * NE;
    size_t mbase = ((size_t)b * NN + qi) * NN;
    float s[16];
    for (int i = 0; i < 16; i++) {
        int kk = lane + 64 * i;
        const float* krow = kbh + (size_t)kk * HD;
        float dot = 0.f;
        for (int d = 0; d < 64; d++) dot += qf[d] * krow[d];
        const float* e = efrow + (size_t)kk * NE;
        float bias = b2s[h];
        for (int o = 0; o < 16; o++) {
            float a = b1s[o];
            for (int f = 0; f < 16; f++) a += e[f] * w1[f][o];
            float eh = (a > 0.f) ? a : (__expf(a) - 1.f);  // ELU
            bias += eh * w2[o][h];
        }
        float l = dot * 0.125f + bias;
        size_t p = mbase + kk;
        bool msk;
        if (mode == 3)      msk = ((const unsigned int*)mask)[2 * p] != 0u;      // int64 low word
        else if (mode == 2) msk = ((const float*)mask)[p] != 0.0f;
        else if (mode == 1) msk = ((const unsigned char*)mask)[p] != 0;
        else                msk = ((const int*)mask)[p] != 0;
        s[i] = msk ? -1e30f : l;
    }
    float mx = s[0];
    for (int i = 1; i < 16; i++) mx = fmaxf(mx, s[i]);
    for (int off = 1; off < 64; off <<= 1) mx = fmaxf(mx, __shfl_xor(mx, off));
    float sum = 0.f;
    for (int i = 0; i < 16; i++) {
        float p = (s[i] < -1e29f) ? 0.f : __expf(s[i] - mx);
        s[i] = p; sum += p;
    }
    for (int off = 1; off < 64; off <<= 1) sum += __shfl_xor(sum, off);
    float inv = (sum > 0.f) ? 1.f / sum : 0.f;  // fully-masked row -> zeros (nan_to_num)
    size_t rowbase = (size_t)row * NN;
    for (int i = 0; i < 16; i++)
        attn[rowbase + lane + 64 * i] = s[i] * inv;
}

// ---- K3: attn @ V -> oattn (fp32), one thread per (b,tok,h,d) ----
__global__ __launch_bounds__(256) void k_av_f(
    const float* __restrict__ attn, const float* __restrict__ vt, float* __restrict__ oattn) {
    int t = blockIdx.x * 256 + threadIdx.x;
    int m = t >> 9, n = t & 511;              // m = b*N+tok, n = h*64+d
    int b = m >> 10, tok = m & 1023, h = n >> 6, d = n & 63;
    const float* arow = attn + ((size_t)(b * NHD + h) * NN + tok) * NN;
    const float* vrow = vt + ((size_t)(b * NHD + h) * HD + d) * NN;
    float acc = 0.f;
    for (int kk = 0; kk < NN; kk++) acc += arow[kk] * vrow[kk];
    oattn[(size_t)m * HID + n] = acc;
}

// ---- K4: output projection (fp32 out), one thread per element ----
__global__ __launch_bounds__(256) void k_oproj_f(
    const float* __restrict__ oa, const float* __restrict__ Wo,
    const float* __restrict__ bo, float* __restrict__ out) {
    int t = blockIdx.x * 256 + threadIdx.x;
    int m = t >> 9, n = t & 511;
    const float* ar = oa + (size_t)m * HID;
    float acc = bo[n];
    for (int k = 0; k < HID; k++) acc += ar[k] * Wo[(size_t)k * HID + n];
    out[(size_t)m * HID + n] = acc;
}

extern "C" void kernel_launch(void* const* d_in, const int* in_sizes, int n_in,
                              void* d_out, int out_size, void* d_ws, size_t ws_size,
                              hipStream_t stream) {
    (void)in_sizes; (void)n_in; (void)out_size; (void)ws_size;
    const float* x   = (const float*)d_in[0];
    const float* ef  = (const float*)d_in[1];
    const void*  msk = d_in[2];
    const float* Wq  = (const float*)d_in[3];
    const float* bq  = (const float*)d_in[4];
    const float* Wk  = (const float*)d_in[5];
    const float* bk  = (const float*)d_in[6];
    const float* Wv  = (const float*)d_in[7];
    const float* bv  = (const float*)d_in[8];
    const float* Wo  = (const float*)d_in[9];
    const float* bo  = (const float*)d_in[10];
    const float* We1 = (const float*)d_in[11];
    const float* be1 = (const float*)d_in[12];
    const float* We2 = (const float*)d_in[13];
    const float* be2 = (const float*)d_in[14];

    char* ws = (char*)d_ws;
    float* qb    = (float*)(ws + 0);          // 4 MB  (b,h,n,d)
    float* kb    = (float*)(ws + 4194304);    // 4 MB  (b,h,n,d)
    float* vt    = (float*)(ws + 8388608);    // 4 MB  (b,h,d,n)
    float* oattn = (float*)(ws + 12582912);   // 4 MB  (b,n, h*64+d)
    int*   flag  = (int*)(ws + 16777216);     // 4 B   (total 16 MB + 4 B)

    // Output dtype = reference's output dtype = FLOAT32 (harness rule: "else float*").
    float* out0 = (float*)d_out;
    float* attn = out0 + (size_t)NB * NN * HID;  // output 1: (B,H,N,N) fp32

    k_maskdet<<<1, 256, 0, stream>>>((const unsigned int*)msk, flag);
    k_qkv_f<<<12288, 256, 0, stream>>>(x, Wq, Wk, Wv, bq, bk, bv, qb, kb, vt);
    k_escore<<<4096, 256, 0, stream>>>(qb, kb, ef, We1, be1, We2, be2, msk, flag, attn);
    k_av_f<<<4096, 256, 0, stream>>>(attn, vt, oattn);
    k_oproj_f<<<4096, 256, 0, stream>>>(oattn, Wo, bo, out0);
}